// Round 1
// baseline (669.049 us; speedup 1.0000x reference)
//
#include <hip/hip_runtime.h>

// Problem constants
// S=2048, N=8, E=512, C=1024, G=32, CG=32; rows R = S*N = 16384
#define ROWS 16384
#define EDIM 512
#define CDIM 1024

// d_out layout (fp32): [sampled (R*C) | softmax (R*C) | pos (R*E) | neg (R*E)]
#define OFF_SOFT (16384 * 1024)
#define OFF_POS  (2 * 16384 * 1024)
#define OFF_NEG  (2 * 16384 * 1024 + 16384 * 512)

// ---------------------------------------------------------------------------
// K0: transpose W2 (E x C) -> W2T (C x E) so gather-GEMM2 reads are coalesced
// ---------------------------------------------------------------------------
__global__ void transpose_w2_kernel(const float* __restrict__ in,
                                    float* __restrict__ out) {
  __shared__ float tile[32][33];
  const int bx = blockIdx.x * 32;  // c base
  const int by = blockIdx.y * 32;  // e base
  const int tx = threadIdx.x;
  const int ty = threadIdx.y;      // block (32, 8)
#pragma unroll
  for (int i = 0; i < 32; i += 8)
    tile[ty + i][tx] = in[(size_t)(by + ty + i) * CDIM + bx + tx];
  __syncthreads();
#pragma unroll
  for (int i = 0; i < 32; i += 8)
    out[(size_t)(bx + ty + i) * EDIM + by + tx] = tile[tx][ty + i];
}

// ---------------------------------------------------------------------------
// K1: fp32 SGEMM  logits[m,c] = 3*(sum_k x[m,k]*W1[c,k] + b1[c]) + coff[c]
// A (M,K) row-major, B (C,K) row-major (NT layout: K contiguous in both)
// 128x128 tile, BK=16, 256 threads, 8x8 per-thread micro-tile
// ---------------------------------------------------------------------------
#define BM 128
#define BN 128
#define BK 16
#define TM 8
#define TN 8

__global__ __launch_bounds__(256, 2) void gemm1_kernel(
    const float* __restrict__ A, const float* __restrict__ B,
    const float* __restrict__ bias1, const float* __restrict__ coff,
    float* __restrict__ Cout) {
  constexpr int K = EDIM;
  constexpr int Nc = CDIM;
  __shared__ __align__(16) float As[BK][BM + 4];
  __shared__ __align__(16) float Bs[BK][BN + 4];
  const int bm = blockIdx.y * BM;
  const int bn = blockIdx.x * BN;
  const int tid = threadIdx.x;
  const int tx = tid & 15;
  const int ty = tid >> 4;

  float acc[TM][TN] = {};

  const int lrow = tid >> 2;        // 0..63
  const int lk4 = (tid & 3) << 2;   // 0,4,8,12

  for (int k0 = 0; k0 < K; k0 += BK) {
#pragma unroll
    for (int i = 0; i < 2; i++) {
      const int row = lrow + i * 64;
      const float4 va =
          *(const float4*)&A[(size_t)(bm + row) * K + k0 + lk4];
      As[lk4 + 0][row] = va.x;
      As[lk4 + 1][row] = va.y;
      As[lk4 + 2][row] = va.z;
      As[lk4 + 3][row] = va.w;
      const float4 vb =
          *(const float4*)&B[(size_t)(bn + row) * K + k0 + lk4];
      Bs[lk4 + 0][row] = vb.x;
      Bs[lk4 + 1][row] = vb.y;
      Bs[lk4 + 2][row] = vb.z;
      Bs[lk4 + 3][row] = vb.w;
    }
    __syncthreads();
#pragma unroll
    for (int k = 0; k < BK; k++) {
      const float4 a0 = *(const float4*)&As[k][ty * TM];
      const float4 a1 = *(const float4*)&As[k][ty * TM + 4];
      const float4 c0 = *(const float4*)&Bs[k][tx * TN];
      const float4 c1 = *(const float4*)&Bs[k][tx * TN + 4];
      const float a[8] = {a0.x, a0.y, a0.z, a0.w, a1.x, a1.y, a1.z, a1.w};
      const float b[8] = {c0.x, c0.y, c0.z, c0.w, c1.x, c1.y, c1.z, c1.w};
#pragma unroll
      for (int i = 0; i < TM; i++)
#pragma unroll
        for (int j = 0; j < TN; j++)
          acc[i][j] = fmaf(a[i], b[j], acc[i][j]);
    }
    __syncthreads();
  }

#pragma unroll
  for (int i = 0; i < TM; i++) {
    const int row = bm + ty * TM + i;
#pragma unroll
    for (int j4 = 0; j4 < 2; j4++) {
      const int col = bn + tx * TN + j4 * 4;
      const float4 bias4 = *(const float4*)&bias1[col];
      const float4 off4 = *(const float4*)&coff[col];
      float4 o;
      o.x = (acc[i][j4 * 4 + 0] + bias4.x) * 3.0f + off4.x;
      o.y = (acc[i][j4 * 4 + 1] + bias4.y) * 3.0f + off4.y;
      o.z = (acc[i][j4 * 4 + 2] + bias4.z) * 3.0f + off4.z;
      o.w = (acc[i][j4 * 4 + 3] + bias4.w) * 3.0f + off4.w;
      *(float4*)&Cout[(size_t)row * Nc + col] = o;
    }
  }
}

// ---------------------------------------------------------------------------
// K2: one block per (s,n) row.
// Phase A: per-group softmax (in-place logits->softmax), Gumbel argmax i/j,
//          sampled = soft + (hard - soft). Half-wave (32-lane) shuffles.
// Phase B: pos_pre[e] = b2[e] + sum_g (wa*W2T[ci] + wb*W2T[cj])[e]; LayerNorm;
//          write pos and neg (identical forward values).
// ---------------------------------------------------------------------------
__global__ __launch_bounds__(256, 2) void sample_kernel(
    float* __restrict__ out_sampled, float* __restrict__ soft_io,
    float* __restrict__ out_pos, float* __restrict__ out_neg,
    const float* __restrict__ g1, const float* __restrict__ g2,
    const float* __restrict__ wI, const float* __restrict__ uI,
    const float* __restrict__ W2T, const float* __restrict__ b2,
    const float* __restrict__ gam, const float* __restrict__ bet) {
  const int r = blockIdx.x;
  const int tid = threadIdx.x;
  const int lane = tid & 63;
  const int wv = tid >> 6;
  const int cg = lane & 31;  // position within group

  __shared__ float s_wa[32], s_wb[32];
  __shared__ int s_ci[32], s_cj[32];
  __shared__ float s_red[4];
  __shared__ float s_red2[4];

  float* lg_row = soft_io + (size_t)r * CDIM;
  float* samp_row = out_sampled + (size_t)r * CDIM;
  const float* g1_row = g1 + (size_t)r * CDIM;
  const float* g2_row = g2 + (size_t)r * CDIM;

#pragma unroll
  for (int it = 0; it < 4; it++) {
    const int c = wv * 256 + it * 64 + lane;  // class index; group is
    const int g = c >> 5;                     // uniform per 32-lane half
    const float logit = lg_row[c];

    // group max
    float m = logit;
#pragma unroll
    for (int off = 16; off >= 1; off >>= 1)
      m = fmaxf(m, __shfl_xor(m, off));
    const float e = expf(logit - m);
    float ssum = e;
#pragma unroll
    for (int off = 16; off >= 1; off >>= 1) ssum += __shfl_xor(ssum, off);
    const float soft = e / ssum;
    const float logp = (logit - m) - logf(ssum);  // mirrors log_softmax

    // argmax(logp + g1), first-index tie-break (matches jnp.argmax)
    float bv = logp + g1_row[c];
    int bi = cg;
#pragma unroll
    for (int off = 16; off >= 1; off >>= 1) {
      const float ov = __shfl_xor(bv, off);
      const int oi = __shfl_xor(bi, off);
      if (ov > bv || (ov == bv && oi < bi)) { bv = ov; bi = oi; }
    }
    // argmax(logp + g2)
    float cv = logp + g2_row[c];
    int cjx = cg;
#pragma unroll
    for (int off = 16; off >= 1; off >>= 1) {
      const float ov = __shfl_xor(cv, off);
      const int oi = __shfl_xor(cjx, off);
      if (ov > cv || (ov == cv && oi < cjx)) { cv = ov; cjx = oi; }
    }

    const float w = wI[(size_t)r * 32 + g];
    const float u = uI[(size_t)r * 32 + g];
    const float interp =
        (cg == bi ? w : 0.0f) + (cg == cjx ? 1.0f - w : 0.0f);
    const float oh = (cg == bi) ? 1.0f : 0.0f;
    const float hard = (u < 1.0f) ? interp : oh;  // INTERP_PROB = 1.0
    samp_row[c] = soft + (hard - soft);  // straight-through forward
    lg_row[c] = soft;                    // overwrite logits with softmax

    if (cg == 0) {
      const bool take = (u < 1.0f);
      s_wa[g] = take ? w : 1.0f;
      s_wb[g] = take ? (1.0f - w) : 0.0f;
      s_ci[g] = g * 32 + bi;
      s_cj[g] = g * 32 + cjx;
    }
  }
  __syncthreads();

  // Phase B: gather-GEMM2 — 64 weighted columns of W2T (L2-resident, 2 MB)
  float ax = 0.0f, ay = 0.0f;
#pragma unroll 4
  for (int g = 0; g < 32; g++) {
    const float2 vi = ((const float2*)(W2T + (size_t)s_ci[g] * EDIM))[tid];
    const float2 vj = ((const float2*)(W2T + (size_t)s_cj[g] * EDIM))[tid];
    const float wa = s_wa[g], wb = s_wb[g];
    ax += wa * vi.x + wb * vj.x;
    ay += wa * vi.y + wb * vj.y;
  }
  const int e0 = tid * 2;
  const float2 b2v = ((const float2*)b2)[tid];
  const float hx = ax + b2v.x;
  const float hy = ay + b2v.y;

  // two-pass LayerNorm over 512 values (2 per thread)
  float ss = hx + hy;
#pragma unroll
  for (int off = 32; off >= 1; off >>= 1) ss += __shfl_xor(ss, off);
  if (lane == 0) s_red[wv] = ss;
  __syncthreads();
  const float mu =
      (s_red[0] + s_red[1] + s_red[2] + s_red[3]) * (1.0f / 512.0f);
  const float dx = hx - mu, dy = hy - mu;
  float vv = dx * dx + dy * dy;
#pragma unroll
  for (int off = 32; off >= 1; off >>= 1) vv += __shfl_xor(vv, off);
  if (lane == 0) s_red2[wv] = vv;
  __syncthreads();
  const float var =
      (s_red2[0] + s_red2[1] + s_red2[2] + s_red2[3]) * (1.0f / 512.0f);
  const float rsig = 1.0f / sqrtf(var + 1e-5f);

  const float2 gv = ((const float2*)gam)[tid];
  const float2 bv2 = ((const float2*)bet)[tid];
  float2 o;
  o.x = dx * rsig * gv.x + bv2.x;
  o.y = dy * rsig * gv.y + bv2.y;
  ((float2*)(out_pos + (size_t)r * EDIM))[tid] = o;
  ((float2*)(out_neg + (size_t)r * EDIM))[tid] = o;  // rev is identity fwd
}

// ---------------------------------------------------------------------------
extern "C" void kernel_launch(void* const* d_in, const int* in_sizes, int n_in,
                              void* d_out, int out_size, void* d_ws,
                              size_t ws_size, hipStream_t stream) {
  const float* x = (const float*)d_in[0];
  const float* W1 = (const float*)d_in[1];
  const float* b1 = (const float*)d_in[2];
  const float* coff = (const float*)d_in[3];
  const float* W2 = (const float*)d_in[4];
  const float* b2 = (const float*)d_in[5];
  const float* gam = (const float*)d_in[6];
  const float* bet = (const float*)d_in[7];
  const float* g1 = (const float*)d_in[8];
  const float* g2 = (const float*)d_in[9];
  const float* wI = (const float*)d_in[10];
  const float* uI = (const float*)d_in[11];

  float* out = (float*)d_out;
  float* out_sampled = out;
  float* soft_io = out + OFF_SOFT;  // holds raw logits between K1 and K2
  float* out_pos = out + OFF_POS;
  float* out_neg = out + OFF_NEG;
  float* W2T = (float*)d_ws;  // 1024*512 fp32 = 2 MB

  hipLaunchKernelGGL(transpose_w2_kernel, dim3(CDIM / 32, EDIM / 32),
                     dim3(32, 8), 0, stream, W2, W2T);
  hipLaunchKernelGGL(gemm1_kernel, dim3(CDIM / BN, ROWS / BM), dim3(256), 0,
                     stream, x, W1, b1, coff, soft_io);
  hipLaunchKernelGGL(sample_kernel, dim3(ROWS), dim3(256), 0, stream,
                     out_sampled, soft_io, out_pos, out_neg, g1, g2, wI, uI,
                     W2T, b2, gam, bet);
}

// Round 2
// 638.802 us; speedup vs baseline: 1.0473x; 1.0473x over previous
//
#include <hip/hip_runtime.h>

// Problem constants: S=2048, N=8, E=512, C=1024, G=32, CG=32; rows R = S*N
#define ROWS 16384
#define EDIM 512
#define CDIM 1024

// d_out layout (fp32): [sampled (R*C) | softmax (R*C) | pos (R*E) | neg (R*E)]
#define OFF_SOFT (16384 * 1024)
#define OFF_POS  (2 * 16384 * 1024)
#define OFF_NEG  (2 * 16384 * 1024 + 16384 * 512)

// ---------------------------------------------------------------------------
// K0: transpose W2 (E x C) -> W2T (C x E) so gather-GEMM2 reads are coalesced
// ---------------------------------------------------------------------------
__global__ void transpose_w2_kernel(const float* __restrict__ in,
                                    float* __restrict__ out) {
  __shared__ float tile[32][33];
  const int bx = blockIdx.x * 32;  // c base
  const int by = blockIdx.y * 32;  // e base
  const int tx = threadIdx.x;
  const int ty = threadIdx.y;      // block (32, 8)
#pragma unroll
  for (int i = 0; i < 32; i += 8)
    tile[ty + i][tx] = in[(size_t)(by + ty + i) * CDIM + bx + tx];
  __syncthreads();
#pragma unroll
  for (int i = 0; i < 32; i += 8)
    out[(size_t)(bx + ty + i) * EDIM + by + tx] = tile[tx][ty + i];
}

// ---------------------------------------------------------------------------
// K1: fp32 SGEMM + FUSED softmax / Gumbel-argmax / sampled epilogue.
// logits[m,c] = 3*(sum_k x[m,k]*W1[c,k] + b1[c]) + coff[c]
// 128x128 tile, BK=16, 256 threads, 8x8 micro-tile. Each 4-thread cluster
// (tx&~3) owns one complete 32-class group per row -> group reductions are
// 2x shfl_xor. Writes softmax + sampled directly, plus a 16B record
// (ci, cj, wa, wb) per (row, group) for the finish kernel.
// ---------------------------------------------------------------------------
#define BM 128
#define BN 128
#define BK 16
#define TM 8
#define TN 8

__global__ __launch_bounds__(256, 2) void gemm1_fused_kernel(
    const float* __restrict__ A, const float* __restrict__ B,
    const float* __restrict__ bias1, const float* __restrict__ coff,
    const float* __restrict__ g1, const float* __restrict__ g2,
    const float* __restrict__ wI, const float* __restrict__ uI,
    float* __restrict__ out_samp, float* __restrict__ out_soft,
    float4* __restrict__ rec) {
  constexpr int K = EDIM;
  __shared__ __align__(16) float As[BK][BM + 4];
  __shared__ __align__(16) float Bs[BK][BN + 4];
  const int bm = blockIdx.y * BM;
  const int bn = blockIdx.x * BN;
  const int tid = threadIdx.x;
  const int tx = tid & 15;
  const int ty = tid >> 4;

  float acc[TM][TN] = {};

  const int lrow = tid >> 2;       // 0..63
  const int lk4 = (tid & 3) << 2;  // 0,4,8,12

  for (int k0 = 0; k0 < K; k0 += BK) {
#pragma unroll
    for (int i = 0; i < 2; i++) {
      const int row = lrow + i * 64;
      const float4 va = *(const float4*)&A[(size_t)(bm + row) * K + k0 + lk4];
      As[lk4 + 0][row] = va.x;
      As[lk4 + 1][row] = va.y;
      As[lk4 + 2][row] = va.z;
      As[lk4 + 3][row] = va.w;
      const float4 vb = *(const float4*)&B[(size_t)(bn + row) * K + k0 + lk4];
      Bs[lk4 + 0][row] = vb.x;
      Bs[lk4 + 1][row] = vb.y;
      Bs[lk4 + 2][row] = vb.z;
      Bs[lk4 + 3][row] = vb.w;
    }
    __syncthreads();
#pragma unroll
    for (int k = 0; k < BK; k++) {
      const float4 a0 = *(const float4*)&As[k][ty * TM];
      const float4 a1 = *(const float4*)&As[k][ty * TM + 4];
      const float4 c0 = *(const float4*)&Bs[k][tx * TN];
      const float4 c1 = *(const float4*)&Bs[k][tx * TN + 4];
      const float a[8] = {a0.x, a0.y, a0.z, a0.w, a1.x, a1.y, a1.z, a1.w};
      const float b[8] = {c0.x, c0.y, c0.z, c0.w, c1.x, c1.y, c1.z, c1.w};
#pragma unroll
      for (int i = 0; i < TM; i++)
#pragma unroll
        for (int j = 0; j < TN; j++)
          acc[i][j] = fmaf(a[i], b[j], acc[i][j]);
    }
    __syncthreads();
  }

  // ------------------- fused epilogue -------------------
  const int col0 = bn + tx * TN;       // first global class this thread owns
  const int cgbase = (tx & 3) * 8;     // position within 32-class group
  const int g = (bn >> 5) + (tx >> 2); // global group index
  const float4 bias4a = *(const float4*)&bias1[col0];
  const float4 bias4b = *(const float4*)&bias1[col0 + 4];
  const float4 off4a = *(const float4*)&coff[col0];
  const float4 off4b = *(const float4*)&coff[col0 + 4];
  const float bb[8] = {bias4a.x, bias4a.y, bias4a.z, bias4a.w,
                       bias4b.x, bias4b.y, bias4b.z, bias4b.w};
  const float oo[8] = {off4a.x, off4a.y, off4a.z, off4a.w,
                       off4b.x, off4b.y, off4b.z, off4b.w};

#pragma unroll
  for (int i = 0; i < TM; i++) {
    const int row = bm + ty * TM + i;
    float lg[8];
#pragma unroll
    for (int j = 0; j < 8; j++) lg[j] = (acc[i][j] + bb[j]) * 3.0f + oo[j];

    // group max (8 in-thread + 4-lane butterfly)
    float m = lg[0];
#pragma unroll
    for (int j = 1; j < 8; j++) m = fmaxf(m, lg[j]);
    m = fmaxf(m, __shfl_xor(m, 1));
    m = fmaxf(m, __shfl_xor(m, 2));

    float e[8], s = 0.0f;
#pragma unroll
    for (int j = 0; j < 8; j++) {
      e[j] = expf(lg[j] - m);
      s += e[j];
    }
    s += __shfl_xor(s, 1);
    s += __shfl_xor(s, 2);
    const float inv = 1.0f / s;
    const float lse = logf(s);  // logp = (lg - m) - lse (mirrors log_softmax)

    // Gumbel argmaxes (first-index tie-break, matching jnp.argmax)
    const float* g1p = &g1[(size_t)row * CDIM + col0];
    const float* g2p = &g2[(size_t)row * CDIM + col0];
    const float4 gA0 = *(const float4*)g1p;
    const float4 gA1 = *(const float4*)(g1p + 4);
    const float4 gB0 = *(const float4*)g2p;
    const float4 gB1 = *(const float4*)(g2p + 4);
    const float ga[8] = {gA0.x, gA0.y, gA0.z, gA0.w, gA1.x, gA1.y, gA1.z, gA1.w};
    const float gb[8] = {gB0.x, gB0.y, gB0.z, gB0.w, gB1.x, gB1.y, gB1.z, gB1.w};

    float bv = (lg[0] - m) - lse + ga[0];
    int bi = cgbase;
    float cv = (lg[0] - m) - lse + gb[0];
    int cj = cgbase;
#pragma unroll
    for (int j = 1; j < 8; j++) {
      const float lp = (lg[j] - m) - lse;
      const float v1 = lp + ga[j];
      if (v1 > bv) { bv = v1; bi = cgbase + j; }
      const float v2 = lp + gb[j];
      if (v2 > cv) { cv = v2; cj = cgbase + j; }
    }
#pragma unroll
    for (int off = 1; off <= 2; off <<= 1) {
      const float ov = __shfl_xor(bv, off);
      const int oi = __shfl_xor(bi, off);
      if (ov > bv || (ov == bv && oi < bi)) { bv = ov; bi = oi; }
      const float ov2 = __shfl_xor(cv, off);
      const int oi2 = __shfl_xor(cj, off);
      if (ov2 > cv || (ov2 == cv && oi2 < cj)) { cv = ov2; cj = oi2; }
    }

    const float w = wI[(size_t)row * 32 + g];
    const float u = uI[(size_t)row * 32 + g];
    const bool take = (u < 1.0f);  // INTERP_PROB = 1.0

    float so[8], sa[8];
#pragma unroll
    for (int j = 0; j < 8; j++) {
      const float soft = e[j] * inv;
      const int cg = cgbase + j;
      const float interp =
          (cg == bi ? w : 0.0f) + (cg == cj ? 1.0f - w : 0.0f);
      const float oh = (cg == bi) ? 1.0f : 0.0f;
      const float hard = take ? interp : oh;
      so[j] = soft;
      sa[j] = soft + (hard - soft);  // straight-through forward
    }
    float* soft_p = &out_soft[(size_t)row * CDIM + col0];
    float* samp_p = &out_samp[(size_t)row * CDIM + col0];
    *(float4*)soft_p = make_float4(so[0], so[1], so[2], so[3]);
    *(float4*)(soft_p + 4) = make_float4(so[4], so[5], so[6], so[7]);
    *(float4*)samp_p = make_float4(sa[0], sa[1], sa[2], sa[3]);
    *(float4*)(samp_p + 4) = make_float4(sa[4], sa[5], sa[6], sa[7]);

    if ((tx & 3) == 0) {
      const float wa = take ? w : 1.0f;
      const float wb = take ? (1.0f - w) : 0.0f;
      rec[(size_t)row * 32 + g] =
          make_float4(__int_as_float(g * 32 + bi), __int_as_float(g * 32 + cj),
                      wa, wb);
    }
  }
}

// ---------------------------------------------------------------------------
// K2: one block per (s,n) row. Gather-GEMM2 over the 64 selected W2T rows
// (L2-resident, 2 MB) + two-pass LayerNorm; writes pos and neg (identical
// forward values — reverse_gradient is identity in the forward pass).
// ---------------------------------------------------------------------------
__global__ __launch_bounds__(256, 4) void finish_kernel(
    const float4* __restrict__ rec, const float* __restrict__ W2T,
    const float* __restrict__ b2, const float* __restrict__ gam,
    const float* __restrict__ bet, float* __restrict__ out_pos,
    float* __restrict__ out_neg) {
  const int r = blockIdx.x;
  const int tid = threadIdx.x;
  const int lane = tid & 63;
  const int wv = tid >> 6;

  __shared__ float s_wa[32], s_wb[32];
  __shared__ int s_ci[32], s_cj[32];
  __shared__ float s_red[4], s_red2[4];

  if (tid < 32) {
    const float4 f = rec[(size_t)r * 32 + tid];
    s_ci[tid] = __float_as_int(f.x);
    s_cj[tid] = __float_as_int(f.y);
    s_wa[tid] = f.z;
    s_wb[tid] = f.w;
  }
  __syncthreads();

  float ax = 0.0f, ay = 0.0f;
#pragma unroll 4
  for (int g = 0; g < 32; g++) {
    const float2 vi = ((const float2*)(W2T + (size_t)s_ci[g] * EDIM))[tid];
    const float2 vj = ((const float2*)(W2T + (size_t)s_cj[g] * EDIM))[tid];
    const float wa = s_wa[g], wb = s_wb[g];
    ax += wa * vi.x + wb * vj.x;
    ay += wa * vi.y + wb * vj.y;
  }
  const float2 b2v = ((const float2*)b2)[tid];
  const float hx = ax + b2v.x;
  const float hy = ay + b2v.y;

  float ss = hx + hy;
#pragma unroll
  for (int off = 32; off >= 1; off >>= 1) ss += __shfl_xor(ss, off);
  if (lane == 0) s_red[wv] = ss;
  __syncthreads();
  const float mu = (s_red[0] + s_red[1] + s_red[2] + s_red[3]) * (1.0f / 512.0f);
  const float dx = hx - mu, dy = hy - mu;
  float vv = dx * dx + dy * dy;
#pragma unroll
  for (int off = 32; off >= 1; off >>= 1) vv += __shfl_xor(vv, off);
  if (lane == 0) s_red2[wv] = vv;
  __syncthreads();
  const float var =
      (s_red2[0] + s_red2[1] + s_red2[2] + s_red2[3]) * (1.0f / 512.0f);
  const float rsig = 1.0f / sqrtf(var + 1e-5f);

  const float2 gv = ((const float2*)gam)[tid];
  const float2 bv2 = ((const float2*)bet)[tid];
  float2 o;
  o.x = dx * rsig * gv.x + bv2.x;
  o.y = dy * rsig * gv.y + bv2.y;
  ((float2*)(out_pos + (size_t)r * EDIM))[tid] = o;
  ((float2*)(out_neg + (size_t)r * EDIM))[tid] = o;
}

// ---------------------------------------------------------------------------
extern "C" void kernel_launch(void* const* d_in, const int* in_sizes, int n_in,
                              void* d_out, int out_size, void* d_ws,
                              size_t ws_size, hipStream_t stream) {
  const float* x = (const float*)d_in[0];
  const float* W1 = (const float*)d_in[1];
  const float* b1 = (const float*)d_in[2];
  const float* coff = (const float*)d_in[3];
  const float* W2 = (const float*)d_in[4];
  const float* b2 = (const float*)d_in[5];
  const float* gam = (const float*)d_in[6];
  const float* bet = (const float*)d_in[7];
  const float* g1 = (const float*)d_in[8];
  const float* g2 = (const float*)d_in[9];
  const float* wI = (const float*)d_in[10];
  const float* uI = (const float*)d_in[11];

  float* out = (float*)d_out;
  float* out_sampled = out;
  float* out_soft = out + OFF_SOFT;
  float* out_pos = out + OFF_POS;
  float* out_neg = out + OFF_NEG;

  float* W2T = (float*)d_ws;                       // 2 MB
  float4* rec = (float4*)((char*)d_ws + (size_t)CDIM * EDIM * 4);  // 8 MB

  hipLaunchKernelGGL(transpose_w2_kernel, dim3(CDIM / 32, EDIM / 32),
                     dim3(32, 8), 0, stream, W2, W2T);
  hipLaunchKernelGGL(gemm1_fused_kernel, dim3(CDIM / BN, ROWS / BM), dim3(256),
                     0, stream, x, W1, b1, coff, g1, g2, wI, uI, out_sampled,
                     out_soft, rec);
  hipLaunchKernelGGL(finish_kernel, dim3(ROWS), dim3(256), 0, stream, rec, W2T,
                     b2, gam, bet, out_pos, out_neg);
}